// Round 1
// baseline (451.410 us; speedup 1.0000x reference)
//
#include <hip/hip_runtime.h>

typedef __bf16 bf16;
typedef bf16 bf16x8 __attribute__((ext_vector_type(8)));
typedef bf16 bf16x4 __attribute__((ext_vector_type(4)));
typedef float f32x4 __attribute__((ext_vector_type(4)));

#define B_ 4
#define N1 4096
#define N2 256
#define DIM 1024
#define HEADS 16
#define DH 64
#define INNER 1024

// ---------------------------------------------------------------------------
// LayerNorm: fp32 (rows x 1024) -> bf16, one block per row
// ---------------------------------------------------------------------------
__global__ __launch_bounds__(256) void ln_kernel(const float* __restrict__ src,
                                                 const float* __restrict__ w,
                                                 const float* __restrict__ bb,
                                                 bf16* __restrict__ dst) {
  int row = blockIdx.x, tid = threadIdx.x;
  const float4* p = (const float4*)(src + (size_t)row * DIM);
  float4 v = p[tid];
  float s = v.x + v.y + v.z + v.w;
  float sq = v.x * v.x + v.y * v.y + v.z * v.z + v.w * v.w;
  for (int off = 32; off; off >>= 1) {
    s += __shfl_down(s, off, 64);
    sq += __shfl_down(sq, off, 64);
  }
  __shared__ float red[8];
  int wv = tid >> 6;
  if ((tid & 63) == 0) { red[wv * 2] = s; red[wv * 2 + 1] = sq; }
  __syncthreads();
  s  = red[0] + red[2] + red[4] + red[6];
  sq = red[1] + red[3] + red[5] + red[7];
  float mu = s * (1.0f / DIM);
  float var = sq * (1.0f / DIM) - mu * mu;
  float r = rsqrtf(var + 1e-5f);
  float4 wv4 = ((const float4*)w)[tid];
  float4 bv4 = ((const float4*)bb)[tid];
  bf16x4 o;
  o[0] = (bf16)((v.x - mu) * r * wv4.x + bv4.x);
  o[1] = (bf16)((v.y - mu) * r * wv4.y + bv4.y);
  o[2] = (bf16)((v.z - mu) * r * wv4.z + bv4.z);
  o[3] = (bf16)((v.w - mu) * r * wv4.w + bv4.w);
  *(bf16x4*)(dst + (size_t)row * DIM + tid * 4) = o;
}

// ---------------------------------------------------------------------------
// Weight transpose + cast: src fp32 (K x N) -> dst bf16 (N x K)
// ---------------------------------------------------------------------------
__global__ __launch_bounds__(256) void transpose_w(const float* __restrict__ src,
                                                   bf16* __restrict__ dst,
                                                   int K, int N) {
  __shared__ float tile[32][33];
  int x = threadIdx.x, y = threadIdx.y;
  int n0 = blockIdx.x * 32, k0 = blockIdx.y * 32;
  for (int j = 0; j < 4; j++)
    tile[y + 8 * j][x] = src[(size_t)(k0 + y + 8 * j) * N + n0 + x];
  __syncthreads();
  for (int j = 0; j < 4; j++)
    dst[(size_t)(n0 + y + 8 * j) * K + k0 + x] = (bf16)tile[x][y + 8 * j];
}

// ---------------------------------------------------------------------------
// V transpose: kv bf16 (b*4096 x 2048), cols [1024..2048) -> vt (b*1024 x 4096)
// vt[(b*1024 + h*64+dh)*4096 + key]
// ---------------------------------------------------------------------------
__global__ __launch_bounds__(256) void transpose_v(const bf16* __restrict__ kv,
                                                   bf16* __restrict__ vt) {
  __shared__ bf16 tile[32][33];
  int x = threadIdx.x, y = threadIdx.y;
  int key0 = blockIdx.x * 32, c0 = blockIdx.y * 32, b = blockIdx.z;
  for (int j = 0; j < 4; j++)
    tile[y + 8 * j][x] =
        kv[(size_t)(b * N1 + key0 + y + 8 * j) * 2048 + 1024 + c0 + x];
  __syncthreads();
  for (int j = 0; j < 4; j++)
    vt[(size_t)(b * 1024 + c0 + y + 8 * j) * N1 + key0 + x] = tile[x][y + 8 * j];
}

// ---------------------------------------------------------------------------
// GEMM C = A(MxK) @ Bt(NxK)^T, bf16 in, fp32 acc. 128x128 tile, BK=32.
// MODE 0: store bf16    MODE 1: AdaLN modulation * attn_scale, store bf16
// MODE 2: store fp32
// LDS XOR swizzle: phys 8-elem block = logical ^ ((row>>1)&3)  (64B rows)
// ---------------------------------------------------------------------------
template <int MODE>
__global__ __launch_bounds__(256) void gemm_bf16(
    const bf16* __restrict__ A, const bf16* __restrict__ Bt,
    void* __restrict__ Cout, int M, int N, int K,
    const float* __restrict__ shiftp, const float* __restrict__ scalep) {
  __shared__ __align__(16) bf16 As[128 * 32];
  __shared__ __align__(16) bf16 Bs[128 * 32];
  int tid = threadIdx.x;
  int lane = tid & 63, wv = tid >> 6;
  int wr = wv >> 1, wc = wv & 1;
  int quad = lane >> 4, lr = lane & 15;
  int m0 = blockIdx.y * 128, n0 = blockIdx.x * 128;
  f32x4 acc[4][4] = {};
  for (int kt = 0; kt < K; kt += 32) {
    __syncthreads();
    for (int i = tid; i < 512; i += 256) {
      int row = i >> 2, cb = i & 3;
      int pb = cb ^ ((row >> 1) & 3);
      *(uint4*)&As[row * 32 + pb * 8] =
          *(const uint4*)&A[(size_t)(m0 + row) * K + kt + cb * 8];
      *(uint4*)&Bs[row * 32 + pb * 8] =
          *(const uint4*)&Bt[(size_t)(n0 + row) * K + kt + cb * 8];
    }
    __syncthreads();
    bf16x8 af[4], bfr[4];
    for (int im = 0; im < 4; im++) {
      int row = wr * 64 + im * 16 + lr;
      af[im] = *(const bf16x8*)&As[row * 32 + (quad ^ ((row >> 1) & 3)) * 8];
    }
    for (int in = 0; in < 4; in++) {
      int row = wc * 64 + in * 16 + lr;
      bfr[in] = *(const bf16x8*)&Bs[row * 32 + (quad ^ ((row >> 1) & 3)) * 8];
    }
    for (int im = 0; im < 4; im++)
      for (int in = 0; in < 4; in++)
        acc[im][in] = __builtin_amdgcn_mfma_f32_16x16x32_bf16(
            af[im], bfr[in], acc[im][in], 0, 0, 0);
  }
  for (int im = 0; im < 4; im++)
    for (int in = 0; in < 4; in++) {
      int col = n0 + wc * 64 + in * 16 + lr;
      for (int r = 0; r < 4; r++) {
        int row = m0 + wr * 64 + im * 16 + quad * 4 + r;
        float v = acc[im][in][r];
        if (MODE == 0) {
          ((bf16*)Cout)[(size_t)row * N + col] = (bf16)v;
        } else if (MODE == 1) {
          int bb = row >> 8, hh = col >> 6;  // 256 latents/batch, 64/head
          float sc = scalep[bb * 16 + hh], sh = shiftp[bb * 16 + hh];
          ((bf16*)Cout)[(size_t)row * N + col] =
              (bf16)((v * (1.0f + sc) + sh) * 0.125f);  // fold attn_scale
        } else {
          ((float*)Cout)[(size_t)row * N + col] = v;
        }
      }
    }
}

// ---------------------------------------------------------------------------
// Flash attention: block = (b, h, 64-query tile), 4 waves x 16 queries.
// Online softmax; C-layout rows = 4*quad+r, cols = lane&15.
// LDS tiles pitch 64, XOR swizzle phys blk = logical ^ (row&7)  (128B rows)
// ---------------------------------------------------------------------------
__global__ __launch_bounds__(256) void attn_kernel(const bf16* __restrict__ q,
                                                   const bf16* __restrict__ kv,
                                                   const bf16* __restrict__ vt,
                                                   bf16* __restrict__ out) {
  int b = blockIdx.z, h = blockIdx.y, qt = blockIdx.x;
  int tid = threadIdx.x, lane = tid & 63, wv = tid >> 6;
  int quad = lane >> 4, lr = lane & 15;
  __shared__ __align__(16) bf16 Qs[64 * 64];
  __shared__ __align__(16) bf16 Ks[64 * 64];
  __shared__ __align__(16) bf16 Vs[64 * 64];   // [dh][key]
  __shared__ __align__(16) bf16 Ps[4][16 * 64];
  int q0 = qt * 64;

  const bf16* qg = q + (size_t)(b * N2 + q0) * INNER + h * DH;
  for (int i = tid; i < 512; i += 256) {
    int row = i >> 3, cb = i & 7;
    *(uint4*)&Qs[row * 64 + (cb ^ (row & 7)) * 8] =
        *(const uint4*)&qg[(size_t)row * INNER + cb * 8];
  }
  __syncthreads();
  bf16x8 aQ[2];
  {
    int row = wv * 16 + lr;
    for (int kk = 0; kk < 2; kk++)
      aQ[kk] = *(const bf16x8*)&Qs[row * 64 + ((quad + 4 * kk) ^ (row & 7)) * 8];
  }
  float m_r[4], l_r[4];
  f32x4 oacc[4] = {};
  for (int r = 0; r < 4; r++) { m_r[r] = -1e30f; l_r[r] = 0.0f; }

  const bf16* kg = kv + (size_t)(b * N1) * 2048 + h * DH;
  const bf16* vg = vt + (size_t)((b * HEADS + h) * DH) * N1;

  for (int t = 0; t < N1 / 64; t++) {
    int key0 = t * 64;
    __syncthreads();
    for (int i = tid; i < 512; i += 256) {
      int row = i >> 3, cb = i & 7;
      int pb = (cb ^ (row & 7)) * 8;
      *(uint4*)&Ks[row * 64 + pb] =
          *(const uint4*)&kg[(size_t)(key0 + row) * 2048 + cb * 8];
      *(uint4*)&Vs[row * 64 + pb] =
          *(const uint4*)&vg[(size_t)row * N1 + key0 + cb * 8];
    }
    __syncthreads();

    f32x4 s[4] = {};
    for (int kk = 0; kk < 2; kk++)
      for (int nt = 0; nt < 4; nt++) {
        int row = nt * 16 + lr;
        bf16x8 bk =
            *(const bf16x8*)&Ks[row * 64 + ((quad + 4 * kk) ^ (row & 7)) * 8];
        s[nt] = __builtin_amdgcn_mfma_f32_16x16x32_bf16(aQ[kk], bk, s[nt], 0, 0, 0);
      }

    float p_arr[4][4], alpha[4];
    for (int r = 0; r < 4; r++) {
      float mx = fmaxf(fmaxf(s[0][r], s[1][r]), fmaxf(s[2][r], s[3][r]));
      for (int off = 8; off; off >>= 1) mx = fmaxf(mx, __shfl_xor(mx, off, 16));
      float mn = fmaxf(m_r[r], mx);
      alpha[r] = __expf(m_r[r] - mn);
      float sum = 0.0f;
      for (int nt = 0; nt < 4; nt++) {
        p_arr[nt][r] = __expf(s[nt][r] - mn);
        sum += p_arr[nt][r];
      }
      for (int off = 8; off; off >>= 1) sum += __shfl_xor(sum, off, 16);
      l_r[r] = l_r[r] * alpha[r] + sum;
      m_r[r] = mn;
    }
    for (int in = 0; in < 4; in++)
      for (int r = 0; r < 4; r++) oacc[in][r] *= alpha[r];

    bf16* ps = Ps[wv];
    for (int nt = 0; nt < 4; nt++)
      for (int r = 0; r < 4; r++) {
        int row = quad * 4 + r, col = nt * 16 + lr;
        ps[row * 64 + ((col >> 3) ^ (row & 7)) * 8 + (col & 7)] =
            (bf16)p_arr[nt][r];
      }
    bf16x8 aP[2];
    for (int kk = 0; kk < 2; kk++)
      aP[kk] = *(const bf16x8*)&ps[lr * 64 + ((quad + 4 * kk) ^ (lr & 7)) * 8];

    for (int kk = 0; kk < 2; kk++)
      for (int in = 0; in < 4; in++) {
        int row = in * 16 + lr;
        bf16x8 bv =
            *(const bf16x8*)&Vs[row * 64 + ((quad + 4 * kk) ^ (row & 7)) * 8];
        oacc[in] = __builtin_amdgcn_mfma_f32_16x16x32_bf16(aP[kk], bv, oacc[in], 0, 0, 0);
      }
  }

  bf16* og = out + (size_t)(b * N2 + q0 + wv * 16) * INNER + h * DH;
  for (int r = 0; r < 4; r++) {
    float inv = 1.0f / l_r[r];
    for (int in = 0; in < 4; in++)
      og[(size_t)(quad * 4 + r) * INNER + in * 16 + lr] =
          (bf16)(oacc[in][r] * inv);
  }
}

// ---------------------------------------------------------------------------
extern "C" void kernel_launch(void* const* d_in, const int* in_sizes, int n_in,
                              void* d_out, int out_size, void* d_ws,
                              size_t ws_size, hipStream_t stream) {
  const float* x       = (const float*)d_in[0];
  const float* latents = (const float*)d_in[1];
  const float* shift   = (const float*)d_in[2];
  const float* scale   = (const float*)d_in[3];
  const float* ln1w    = (const float*)d_in[4];
  const float* ln1b    = (const float*)d_in[5];
  const float* ln2w    = (const float*)d_in[6];
  const float* ln2b    = (const float*)d_in[7];
  const float* Wq      = (const float*)d_in[8];
  const float* Wkv     = (const float*)d_in[9];
  const float* Wout    = (const float*)d_in[10];

  char* ws = (char*)d_ws;
  bf16* xn    = (bf16*)(ws);                    // 16384x1024  (33.5 MB)
  bf16* lnl   = (bf16*)(ws + 33554432);         // 1024x1024
  bf16* qb    = (bf16*)(ws + 35651584);         // 1024x1024
  bf16* kvb   = (bf16*)(ws + 37748736);         // 16384x2048  (67 MB)
  bf16* vtb   = (bf16*)(ws + 104857600);        // 4096x4096   (33.5 MB)
  bf16* aob   = (bf16*)(ws + 138412032);        // 1024x1024
  bf16* WqT   = (bf16*)(ws + 140509184);        // 1024x1024
  bf16* WkvT  = (bf16*)(ws + 142606336);        // 2048x1024
  bf16* WoutT = (bf16*)(ws + 146800640);        // 1024x1024  -> total ~142 MB

  dim3 tb(32, 8);
  transpose_w<<<dim3(32, 32), tb, 0, stream>>>(Wq, WqT, 1024, 1024);
  transpose_w<<<dim3(64, 32), tb, 0, stream>>>(Wkv, WkvT, 1024, 2048);
  transpose_w<<<dim3(32, 32), tb, 0, stream>>>(Wout, WoutT, 1024, 1024);

  ln_kernel<<<16384, 256, 0, stream>>>(x, ln1w, ln1b, xn);
  ln_kernel<<<1024, 256, 0, stream>>>(latents, ln2w, ln2b, lnl);

  gemm_bf16<0><<<dim3(16, 128), 256, 0, stream>>>(xn, WkvT, kvb, 16384, 2048,
                                                  1024, nullptr, nullptr);
  transpose_v<<<dim3(128, 32, 4), tb, 0, stream>>>(kvb, vtb);
  gemm_bf16<1><<<dim3(8, 8), 256, 0, stream>>>(lnl, WqT, qb, 1024, 1024, 1024,
                                               shift, scale);
  attn_kernel<<<dim3(4, 16, 4), 256, 0, stream>>>(qb, kvb, vtb, aob);
  gemm_bf16<2><<<dim3(8, 8), 256, 0, stream>>>(aob, WoutT, d_out, 1024, 1024,
                                               1024, nullptr, nullptr);
}

// Round 2
// 373.202 us; speedup vs baseline: 1.2096x; 1.2096x over previous
//
#include <hip/hip_runtime.h>

typedef __bf16 bf16;
typedef bf16 bf16x8 __attribute__((ext_vector_type(8)));
typedef bf16 bf16x4 __attribute__((ext_vector_type(4)));
typedef float f32x4 __attribute__((ext_vector_type(4)));

#define B_ 4
#define N1 4096
#define N2 256
#define DIM 1024
#define HEADS 16
#define DH 64
#define INNER 1024
#define ASPLIT 4
#define KEYS_PER_SPLIT (N1 / ASPLIT)  // 1024
#define SPLIT_ELEMS (4 * 16 * 256 * 64)  // fp32 elems per split partial

// async global->LDS, 16B per lane; LDS dest = wave-uniform base + lane*16
typedef __attribute__((address_space(1))) const void gvoid_t;
typedef __attribute__((address_space(3))) void lvoid_t;
__device__ __forceinline__ void async16(const void* g, void* l) {
  __builtin_amdgcn_global_load_lds((gvoid_t*)g, (lvoid_t*)l, 16, 0, 0);
}

// ---------------------------------------------------------------------------
// LayerNorm: fp32 (rows x 1024) -> bf16, one block per row
// ---------------------------------------------------------------------------
__global__ __launch_bounds__(256) void ln_kernel(const float* __restrict__ src,
                                                 const float* __restrict__ w,
                                                 const float* __restrict__ bb,
                                                 bf16* __restrict__ dst) {
  int row = blockIdx.x, tid = threadIdx.x;
  const float4* p = (const float4*)(src + (size_t)row * DIM);
  float4 v = p[tid];
  float s = v.x + v.y + v.z + v.w;
  float sq = v.x * v.x + v.y * v.y + v.z * v.z + v.w * v.w;
  for (int off = 32; off; off >>= 1) {
    s += __shfl_down(s, off, 64);
    sq += __shfl_down(sq, off, 64);
  }
  __shared__ float red[8];
  int wv = tid >> 6;
  if ((tid & 63) == 0) { red[wv * 2] = s; red[wv * 2 + 1] = sq; }
  __syncthreads();
  s  = red[0] + red[2] + red[4] + red[6];
  sq = red[1] + red[3] + red[5] + red[7];
  float mu = s * (1.0f / DIM);
  float var = sq * (1.0f / DIM) - mu * mu;
  float r = rsqrtf(var + 1e-5f);
  float4 wv4 = ((const float4*)w)[tid];
  float4 bv4 = ((const float4*)bb)[tid];
  bf16x4 o;
  o[0] = (bf16)((v.x - mu) * r * wv4.x + bv4.x);
  o[1] = (bf16)((v.y - mu) * r * wv4.y + bv4.y);
  o[2] = (bf16)((v.z - mu) * r * wv4.z + bv4.z);
  o[3] = (bf16)((v.w - mu) * r * wv4.w + bv4.w);
  *(bf16x4*)(dst + (size_t)row * DIM + tid * 4) = o;
}

// ---------------------------------------------------------------------------
// Weight transpose + cast: src fp32 (K x N) -> dst bf16 (N x K)
// ---------------------------------------------------------------------------
__global__ __launch_bounds__(256) void transpose_w(const float* __restrict__ src,
                                                   bf16* __restrict__ dst,
                                                   int K, int N) {
  __shared__ float tile[32][33];
  int x = threadIdx.x, y = threadIdx.y;
  int n0 = blockIdx.x * 32, k0 = blockIdx.y * 32;
  for (int j = 0; j < 4; j++)
    tile[y + 8 * j][x] = src[(size_t)(k0 + y + 8 * j) * N + n0 + x];
  __syncthreads();
  for (int j = 0; j < 4; j++)
    dst[(size_t)(n0 + y + 8 * j) * K + k0 + x] = (bf16)tile[x][y + 8 * j];
}

// ---------------------------------------------------------------------------
// V transpose: vraw bf16 (b*4096 keys x 1024 c) -> vt[(b*1024 + c)*4096 + key]
// 64x64 tiles, vectorized 16B loads/stores
// ---------------------------------------------------------------------------
__global__ __launch_bounds__(256) void transpose_v(const bf16* __restrict__ vraw,
                                                   bf16* __restrict__ vt) {
  __shared__ __align__(16) bf16 tile[64][72];  // 144B rows: 16B-aligned
  int b = blockIdx.z;
  int key0 = blockIdx.x * 64, c0 = blockIdx.y * 64;
  for (int i = threadIdx.x; i < 512; i += 256) {
    int k = i >> 3, cb = i & 7;
    *(bf16x8*)&tile[k][cb * 8] =
        *(const bf16x8*)&vraw[(size_t)(b * N1 + key0 + k) * 1024 + c0 + cb * 8];
  }
  __syncthreads();
  for (int i = threadIdx.x; i < 512; i += 256) {
    int c = i >> 3, kb = i & 7;
    bf16x8 o;
    for (int j = 0; j < 8; j++) o[j] = tile[kb * 8 + j][c];
    *(bf16x8*)&vt[(size_t)(b * 1024 + c0 + c) * N1 + key0 + kb * 8] = o;
  }
}

// ---------------------------------------------------------------------------
// GEMM C = A(MxK) @ Bt(NxK)^T, bf16 in, fp32 acc. 128x128 tile, BK=32.
// Staging via global_load_lds (16B/lane); LDS swizzle achieved by permuting the
// GLOBAL column block per lane (phys blk pb holds logical pb ^ ((row>>1)&3)).
// MODE 0: split store bf16 (cols<1024 -> Cout, else Cout2)
// MODE 1: AdaLN modulation * attn_scale * log2e, store bf16
// MODE 2: store fp32
// ---------------------------------------------------------------------------
template <int MODE>
__global__ __launch_bounds__(256) void gemm_bf16(
    const bf16* __restrict__ A, const bf16* __restrict__ Bt,
    void* __restrict__ Cout, void* __restrict__ Cout2, int M, int N, int K,
    const float* __restrict__ shiftp, const float* __restrict__ scalep) {
  __shared__ __align__(16) bf16 As[128 * 32];
  __shared__ __align__(16) bf16 Bs[128 * 32];
  int tid = threadIdx.x;
  int lane = tid & 63, wv = tid >> 6;
  int wr = wv >> 1, wc = wv & 1;
  int quad = lane >> 4, lr = lane & 15;
  int m0 = blockIdx.y * 128, n0 = blockIdx.x * 128;
  int srow = lane >> 2, scb = lane & 3;
  f32x4 acc[4][4] = {};
  for (int kt = 0; kt < K; kt += 32) {
    __syncthreads();
    for (int j = 0; j < 2; j++) {
      int r0 = j * 64 + wv * 16;
      int ra = r0 + srow;
      int ca = (scb ^ ((ra >> 1) & 3)) * 8;
      async16(&A[(size_t)(m0 + ra) * K + kt + ca], &As[r0 * 32]);
      async16(&Bt[(size_t)(n0 + ra) * K + kt + ca], &Bs[r0 * 32]);
    }
    __syncthreads();
    bf16x8 af[4], bfr[4];
    for (int im = 0; im < 4; im++) {
      int row = wr * 64 + im * 16 + lr;
      af[im] = *(const bf16x8*)&As[row * 32 + (quad ^ ((row >> 1) & 3)) * 8];
    }
    for (int in = 0; in < 4; in++) {
      int row = wc * 64 + in * 16 + lr;
      bfr[in] = *(const bf16x8*)&Bs[row * 32 + (quad ^ ((row >> 1) & 3)) * 8];
    }
    for (int im = 0; im < 4; im++)
      for (int in = 0; in < 4; in++)
        acc[im][in] = __builtin_amdgcn_mfma_f32_16x16x32_bf16(
            af[im], bfr[in], acc[im][in], 0, 0, 0);
  }
  for (int im = 0; im < 4; im++)
    for (int in = 0; in < 4; in++) {
      int col = n0 + wc * 64 + in * 16 + lr;
      for (int r = 0; r < 4; r++) {
        int row = m0 + wr * 64 + im * 16 + quad * 4 + r;
        float v = acc[im][in][r];
        if (MODE == 0) {
          if (col < 1024)
            ((bf16*)Cout)[(size_t)row * 1024 + col] = (bf16)v;
          else
            ((bf16*)Cout2)[(size_t)row * 1024 + col - 1024] = (bf16)v;
        } else if (MODE == 1) {
          int bb = row >> 8, hh = col >> 6;  // 256 latents/batch, 64/head
          float sc = scalep[bb * 16 + hh], sh = shiftp[bb * 16 + hh];
          // fold attn_scale (0.125) AND log2(e) so softmax uses exp2
          ((bf16*)Cout)[(size_t)row * N + col] =
              (bf16)((v * (1.0f + sc) + sh) * 0.18033688011112042f);
        } else {
          ((float*)Cout)[(size_t)row * N + col] = v;
        }
      }
    }
}

// ---------------------------------------------------------------------------
// Flash attention, split-K over keys (ASPLIT splits of 1024 keys).
// block = (b, h, qtile, split); 4 waves x 16 queries. Scores in log2 domain.
// Writes unnormalized fp32 partials + (m,l) per query row.
// LDS 24KB: Ks, Vs, QP (Q tile unioned with per-wave P scratch).
// ---------------------------------------------------------------------------
__global__ __launch_bounds__(256) void attn_kernel(const bf16* __restrict__ q,
                                                   const bf16* __restrict__ kb,
                                                   const bf16* __restrict__ vt,
                                                   float* __restrict__ opA,
                                                   float* __restrict__ opB,
                                                   float* __restrict__ ml) {
  int b = blockIdx.z, h = blockIdx.y;
  int qt = blockIdx.x & 3, sp = blockIdx.x >> 2;
  int tid = threadIdx.x, lane = tid & 63, wv = tid >> 6;
  int quad = lane >> 4, lr = lane & 15;
  __shared__ __align__(16) bf16 Ks[64 * 64];
  __shared__ __align__(16) bf16 Vs[64 * 64];  // [dh][key]
  __shared__ __align__(16) bf16 QP[64 * 64];  // Q tile, then per-wave P scratch
  int q0 = qt * 64;
  int srow = lane >> 3, sblk = lane & 7;

  // stage Q (64 q-rows x 64 d), swizzle via global-side block permutation
  const bf16* qg = q + (size_t)(b * N2 + q0) * INNER + h * DH;
  for (int j = 0; j < 2; j++) {
    int r0 = j * 32 + wv * 8;
    int r = r0 + srow;
    async16(&qg[(size_t)r * INNER + (sblk ^ (r & 7)) * 8], &QP[r0 * 64]);
  }
  __syncthreads();
  bf16x8 aQ[2];
  {
    int row = wv * 16 + lr;
    for (int kk = 0; kk < 2; kk++)
      aQ[kk] = *(const bf16x8*)&QP[row * 64 + ((quad + 4 * kk) ^ (row & 7)) * 8];
  }
  float m_r[4], l_r[4];
  f32x4 oacc[4] = {};
  for (int r = 0; r < 4; r++) { m_r[r] = -1e30f; l_r[r] = 0.0f; }

  const bf16* kg = kb + (size_t)(b * N1) * 1024 + h * DH;
  const bf16* vg = vt + (size_t)((b * HEADS + h) * DH) * N1;

  for (int t = 0; t < KEYS_PER_SPLIT / 64; t++) {
    int key0 = sp * KEYS_PER_SPLIT + t * 64;
    __syncthreads();
    for (int j = 0; j < 2; j++) {
      int r0 = j * 32 + wv * 8;
      int r = r0 + srow;
      int cs = (sblk ^ (r & 7)) * 8;
      async16(&kg[(size_t)(key0 + r) * 1024 + cs], &Ks[r0 * 64]);
      async16(&vg[(size_t)r * N1 + key0 + cs], &Vs[r0 * 64]);
    }
    __syncthreads();

    f32x4 s[4] = {};
    for (int kk = 0; kk < 2; kk++)
      for (int nt = 0; nt < 4; nt++) {
        int row = nt * 16 + lr;
        bf16x8 bk =
            *(const bf16x8*)&Ks[row * 64 + ((quad + 4 * kk) ^ (row & 7)) * 8];
        s[nt] = __builtin_amdgcn_mfma_f32_16x16x32_bf16(aQ[kk], bk, s[nt], 0, 0, 0);
      }

    float p_arr[4][4], alpha[4];
    for (int r = 0; r < 4; r++) {
      float mx = fmaxf(fmaxf(s[0][r], s[1][r]), fmaxf(s[2][r], s[3][r]));
      for (int off = 8; off; off >>= 1) mx = fmaxf(mx, __shfl_xor(mx, off, 16));
      float mn = fmaxf(m_r[r], mx);
      alpha[r] = exp2f(m_r[r] - mn);
      float sum = 0.0f;
      for (int nt = 0; nt < 4; nt++) {
        p_arr[nt][r] = exp2f(s[nt][r] - mn);
        sum += p_arr[nt][r];
      }
      for (int off = 8; off; off >>= 1) sum += __shfl_xor(sum, off, 16);
      l_r[r] = l_r[r] * alpha[r] + sum;
      m_r[r] = mn;
    }
    for (int in = 0; in < 4; in++)
      for (int r = 0; r < 4; r++) oacc[in][r] *= alpha[r];

    bf16* ps = QP + wv * 1024;  // 16x64 per-wave scratch (Q already in regs)
    for (int nt = 0; nt < 4; nt++)
      for (int r = 0; r < 4; r++) {
        int row = quad * 4 + r, col = nt * 16 + lr;
        ps[row * 64 + ((col >> 3) ^ (row & 7)) * 8 + (col & 7)] =
            (bf16)p_arr[nt][r];
      }
    bf16x8 aP[2];
    for (int kk = 0; kk < 2; kk++)
      aP[kk] = *(const bf16x8*)&ps[lr * 64 + ((quad + 4 * kk) ^ (lr & 7)) * 8];

    for (int kk = 0; kk < 2; kk++)
      for (int in = 0; in < 4; in++) {
        int row = in * 16 + lr;
        bf16x8 bv =
            *(const bf16x8*)&Vs[row * 64 + ((quad + 4 * kk) ^ (row & 7)) * 8];
        oacc[in] = __builtin_amdgcn_mfma_f32_16x16x32_bf16(aP[kk], bv, oacc[in], 0, 0, 0);
      }
  }

  // epilogue: unnormalized partials + (m,l)
  float* ob = (sp < 2 ? opA : opB) + (size_t)(sp & 1) * SPLIT_ELEMS;
  size_t rbase = (size_t)(b * HEADS + h) * N2;
  for (int r = 0; r < 4; r++) {
    int qq = q0 + wv * 16 + quad * 4 + r;
    for (int in = 0; in < 4; in++)
      ob[(rbase + qq) * 64 + in * 16 + lr] = oacc[in][r];
    if (lr == 0) {
      float* mlp = ml + ((size_t)sp * (4 * HEADS * N2) + rbase + qq) * 2;
      mlp[0] = m_r[r];
      mlp[1] = l_r[r];
    }
  }
}

// ---------------------------------------------------------------------------
// Combine split-K partials: out = sum_s w_s O_s / sum_s w_s l_s, w_s=2^(m_s-M)
// ---------------------------------------------------------------------------
__global__ __launch_bounds__(256) void combine_kernel(const float* __restrict__ opA,
                                                      const float* __restrict__ opB,
                                                      const float* __restrict__ ml,
                                                      bf16* __restrict__ out) {
  int gid = blockIdx.x * 256 + threadIdx.x;  // 4*16*256*64 threads
  int d = gid & 63;
  int rq = gid >> 6;  // (b*16+h)*256 + q
  int qq = rq & 255, bh = rq >> 8;
  int h = bh & 15, b = bh >> 4;
  float m[ASPLIT], l[ASPLIT];
  for (int s = 0; s < ASPLIT; s++) {
    const float* p = ml + ((size_t)s * (4 * HEADS * N2) + rq) * 2;
    m[s] = p[0];
    l[s] = p[1];
  }
  float M = fmaxf(fmaxf(m[0], m[1]), fmaxf(m[2], m[3]));
  float L = 0.0f, o = 0.0f;
  for (int s = 0; s < ASPLIT; s++) {
    float w = exp2f(m[s] - M);
    L += w * l[s];
    const float* op = (s < 2 ? opA : opB) + (size_t)(s & 1) * SPLIT_ELEMS;
    o += w * op[(size_t)rq * 64 + d];
  }
  out[((size_t)(b * N2 + qq)) * INNER + h * DH + d] = (bf16)(o / L);
}

// ---------------------------------------------------------------------------
extern "C" void kernel_launch(void* const* d_in, const int* in_sizes, int n_in,
                              void* d_out, int out_size, void* d_ws,
                              size_t ws_size, hipStream_t stream) {
  const float* x       = (const float*)d_in[0];
  const float* latents = (const float*)d_in[1];
  const float* shift   = (const float*)d_in[2];
  const float* scale   = (const float*)d_in[3];
  const float* ln1w    = (const float*)d_in[4];
  const float* ln1b    = (const float*)d_in[5];
  const float* ln2w    = (const float*)d_in[6];
  const float* ln2b    = (const float*)d_in[7];
  const float* Wq      = (const float*)d_in[8];
  const float* Wkv     = (const float*)d_in[9];
  const float* Wout    = (const float*)d_in[10];

  char* ws = (char*)d_ws;
  bf16*  xn    = (bf16*)(ws);                // 33.5MB; dead after kv gemm
  float* opA   = (float*)(ws);               //   overlay: splits 0,1 partials
  bf16*  lnl   = (bf16*)(ws + 33554432);     // 2MB; dead after q gemm
  float* ml    = (float*)(ws + 33554432);    //   overlay: (m,l) 0.5MB
  bf16*  qb    = (bf16*)(ws + 35651584);     // 2MB
  bf16*  kb    = (bf16*)(ws + 37748736);     // 33.5MB (K half)
  bf16*  vraw  = (bf16*)(ws + 71303168);     // 33.5MB; dead after transpose_v
  float* opB   = (float*)(ws + 71303168);    //   overlay: splits 2,3 partials
  bf16*  vtb   = (bf16*)(ws + 104857600);    // 33.5MB
  bf16*  aob   = (bf16*)(ws + 138412032);    // 2MB
  bf16*  WqT   = (bf16*)(ws + 140509184);    // 2MB
  bf16*  WkvT  = (bf16*)(ws + 142606336);    // 4MB
  bf16*  WoutT = (bf16*)(ws + 146800640);    // 2MB -> total 148.9MB

  dim3 tb(32, 8);
  transpose_w<<<dim3(32, 32), tb, 0, stream>>>(Wq, WqT, 1024, 1024);
  transpose_w<<<dim3(64, 32), tb, 0, stream>>>(Wkv, WkvT, 1024, 2048);
  transpose_w<<<dim3(32, 32), tb, 0, stream>>>(Wout, WoutT, 1024, 1024);

  ln_kernel<<<16384, 256, 0, stream>>>(x, ln1w, ln1b, xn);
  ln_kernel<<<1024, 256, 0, stream>>>(latents, ln2w, ln2b, lnl);

  gemm_bf16<0><<<dim3(16, 128), 256, 0, stream>>>(xn, WkvT, kb, vraw, 16384,
                                                  2048, 1024, nullptr, nullptr);
  transpose_v<<<dim3(64, 16, 4), 256, 0, stream>>>(vraw, vtb);
  gemm_bf16<1><<<dim3(8, 8), 256, 0, stream>>>(lnl, WqT, qb, nullptr, 1024,
                                               1024, 1024, shift, scale);
  attn_kernel<<<dim3(4 * ASPLIT, 16, 4), 256, 0, stream>>>(qb, kb, vtb, opA,
                                                           opB, ml);
  combine_kernel<<<16384, 256, 0, stream>>>(opA, opB, ml, aob);
  gemm_bf16<2><<<dim3(8, 8), 256, 0, stream>>>(aob, WoutT, d_out, nullptr,
                                               1024, 1024, 1024, nullptr, nullptr);
}

// Round 3
// 311.154 us; speedup vs baseline: 1.4508x; 1.1994x over previous
//
#include <hip/hip_runtime.h>

typedef __bf16 bf16;
typedef bf16 bf16x8 __attribute__((ext_vector_type(8)));
typedef bf16 bf16x4 __attribute__((ext_vector_type(4)));
typedef float f32x4 __attribute__((ext_vector_type(4)));

#define B_ 4
#define N1 4096
#define N2 256
#define DIM 1024
#define HEADS 16
#define DH 64
#define INNER 1024
#define ASPLIT 4
#define KEYS_PER_SPLIT (N1 / ASPLIT)     // 1024
#define SPLIT_ELEMS (4 * 16 * 256 * 64)  // fp32 elems per split partial

// async global->LDS, 16B per lane; LDS dest = wave-uniform base + lane*16
typedef __attribute__((address_space(1))) const void gvoid_t;
typedef __attribute__((address_space(3))) void lvoid_t;
__device__ __forceinline__ void async16(const void* g, void* l) {
  __builtin_amdgcn_global_load_lds((gvoid_t*)g, (lvoid_t*)l, 16, 0, 0);
}

// ---------------------------------------------------------------------------
// LayerNorm: fp32 (rows x 1024) -> bf16. One WAVE per row (no LDS, no barrier).
// ---------------------------------------------------------------------------
__global__ __launch_bounds__(256) void ln_kernel(const float* __restrict__ src,
                                                 const float* __restrict__ w,
                                                 const float* __restrict__ bb,
                                                 bf16* __restrict__ dst) {
  int wv = threadIdx.x >> 6, lane = threadIdx.x & 63;
  int row = blockIdx.x * 4 + wv;
  const float4* p = (const float4*)(src + (size_t)row * DIM);
  float4 v[4];
  for (int j = 0; j < 4; j++) v[j] = p[j * 64 + lane];
  float s = 0.f, sq = 0.f;
  for (int j = 0; j < 4; j++) {
    s += v[j].x + v[j].y + v[j].z + v[j].w;
    sq += v[j].x * v[j].x + v[j].y * v[j].y + v[j].z * v[j].z + v[j].w * v[j].w;
  }
  for (int off = 32; off; off >>= 1) {
    s += __shfl_xor(s, off, 64);
    sq += __shfl_xor(sq, off, 64);
  }
  float mu = s * (1.0f / DIM);
  float var = sq * (1.0f / DIM) - mu * mu;
  float r = rsqrtf(var + 1e-5f);
  for (int j = 0; j < 4; j++) {
    float4 wv4 = ((const float4*)w)[j * 64 + lane];
    float4 bv4 = ((const float4*)bb)[j * 64 + lane];
    bf16x4 o;
    o[0] = (bf16)((v[j].x - mu) * r * wv4.x + bv4.x);
    o[1] = (bf16)((v[j].y - mu) * r * wv4.y + bv4.y);
    o[2] = (bf16)((v[j].z - mu) * r * wv4.z + bv4.z);
    o[3] = (bf16)((v[j].w - mu) * r * wv4.w + bv4.w);
    *(bf16x4*)(dst + (size_t)row * DIM + (j * 64 + lane) * 4) = o;
  }
}

// ---------------------------------------------------------------------------
// All three weight transposes in one launch: fp32 (1024 x N) -> bf16 (N x 1024)
// flat tile id: [0,1024) Wq, [1024,3072) Wkv, [3072,4096) Wout
// ---------------------------------------------------------------------------
__global__ __launch_bounds__(256) void transpose_w_all(
    const float* __restrict__ Wq, const float* __restrict__ Wkv,
    const float* __restrict__ Wout, bf16* __restrict__ WqT,
    bf16* __restrict__ WkvT, bf16* __restrict__ WoutT) {
  __shared__ float tile[32][33];
  int t = blockIdx.x;
  const float* src;
  bf16* dst;
  int N;
  if (t < 1024) { src = Wq; dst = WqT; N = 1024; }
  else if (t < 3072) { t -= 1024; src = Wkv; dst = WkvT; N = 2048; }
  else { t -= 3072; src = Wout; dst = WoutT; N = 1024; }
  int ntiles = N >> 5;
  int n0 = (t % ntiles) * 32, k0 = (t / ntiles) * 32;
  int x = threadIdx.x, y = threadIdx.y;
  for (int j = 0; j < 4; j++)
    tile[y + 8 * j][x] = src[(size_t)(k0 + y + 8 * j) * N + n0 + x];
  __syncthreads();
  for (int j = 0; j < 4; j++)
    dst[(size_t)(n0 + y + 8 * j) * 1024 + k0 + x] = (bf16)tile[x][y + 8 * j];
}

// ---------------------------------------------------------------------------
// GEMM C = A(MxK) @ Bt(Nx K)^T, bf16 in, fp32 acc. 128x128 tile, BK=64.
// Staging via global_load_lds 16B/lane; pitch-64 XOR swizzle (blk ^= row&7).
// MODE 0 (kv): n0<1024 -> K half, direct bf16 stores to Cout (stride 1024);
//              n0>=1024 -> V half, LDS-transposed b128 stores to Cout2 = V^T
//              laid out vt[(b*1024 + c)*4096 + key].
// MODE 1: AdaLN modulation * attn_scale * log2e, store bf16
// MODE 2: store fp32
// ---------------------------------------------------------------------------
template <int MODE>
__global__ __launch_bounds__(256) void gemm_bf16(
    const bf16* __restrict__ A, const bf16* __restrict__ Bt,
    void* __restrict__ Cout, void* __restrict__ Cout2, int M, int N, int K,
    const float* __restrict__ shiftp, const float* __restrict__ scalep) {
  __shared__ __align__(16) bf16 smem[128 * 64 * 2];  // As | Bs (32KB)
  bf16* As = smem;
  bf16* Bs = smem + 128 * 64;
  int tid = threadIdx.x;
  int lane = tid & 63, wv = tid >> 6;
  int wr = wv >> 1, wc = wv & 1;
  int quad = lane >> 4, lr = lane & 15;
  int m0 = blockIdx.y * 128, n0 = blockIdx.x * 128;
  f32x4 acc[4][4] = {};
  for (int kt = 0; kt < K; kt += 64) {
    __syncthreads();
    for (int j = 0; j < 4; j++) {
      int idx0 = j * 256 + wv * 64;  // wave-uniform chunk base
      int row = (idx0 >> 3) + (lane >> 3);
      int cb = (lane & 7) ^ (row & 7);  // global col-block for phys blk lane&7
      async16(&A[(size_t)(m0 + row) * K + kt + cb * 8], &As[idx0 * 8]);
      async16(&Bt[(size_t)(n0 + row) * K + kt + cb * 8], &Bs[idx0 * 8]);
    }
    __syncthreads();
    for (int kk = 0; kk < 2; kk++) {
      bf16x8 af[4], bfr[4];
      for (int im = 0; im < 4; im++) {
        int row = wr * 64 + im * 16 + lr;
        af[im] = *(const bf16x8*)&As[row * 64 + ((quad + 4 * kk) ^ (row & 7)) * 8];
      }
      for (int in = 0; in < 4; in++) {
        int row = wc * 64 + in * 16 + lr;
        bfr[in] = *(const bf16x8*)&Bs[row * 64 + ((quad + 4 * kk) ^ (row & 7)) * 8];
      }
      for (int im = 0; im < 4; im++)
        for (int in = 0; in < 4; in++)
          acc[im][in] = __builtin_amdgcn_mfma_f32_16x16x32_bf16(
              af[im], bfr[in], acc[im][in], 0, 0, 0);
    }
  }

  if (MODE == 0 && n0 >= 1024) {
    // V half: transpose through LDS, write V^T with b128 stores
    bf16* Ct = smem;  // 64 x 136 pitch (17KB)
    for (int pass = 0; pass < 2; pass++) {
      __syncthreads();
      for (int inL = 0; inL < 2; inL++) {
        int in = pass * 2 + inL;
        int cc = wc * 32 + inL * 16 + lr;
        for (int im = 0; im < 4; im++) {
          int rb = wr * 64 + im * 16 + quad * 4;
          bf16x4 pk;
          for (int r = 0; r < 4; r++) pk[r] = (bf16)acc[im][in][r];
          *(bf16x4*)&Ct[cc * 136 + rb] = pk;
        }
      }
      __syncthreads();
      for (int k2 = 0; k2 < 4; k2++) {
        int ci = k2 * 256 + tid;
        int cc = ci >> 4, ch = ci & 15;
        uint4 val = *(const uint4*)&Ct[cc * 136 + ch * 8];
        int gco = (cc >> 5) * 64 + pass * 32 + (cc & 31);
        int col = n0 - 1024 + gco;        // 0..1023 within inner dim
        int bb2 = m0 >> 12;               // batch
        int key = (m0 & 4095) + ch * 8;
        *(uint4*)&((bf16*)Cout2)[((size_t)(bb2 * 1024 + col)) * 4096 + key] = val;
      }
    }
    return;
  }

  for (int im = 0; im < 4; im++)
    for (int in = 0; in < 4; in++) {
      int col = n0 + wc * 64 + in * 16 + lr;
      for (int r = 0; r < 4; r++) {
        int row = m0 + wr * 64 + im * 16 + quad * 4 + r;
        float v = acc[im][in][r];
        if (MODE == 0) {
          ((bf16*)Cout)[(size_t)row * 1024 + col] = (bf16)v;
        } else if (MODE == 1) {
          int bb = row >> 8, hh = col >> 6;
          float sc = scalep[bb * 16 + hh], sh = shiftp[bb * 16 + hh];
          // fold attn_scale (0.125) AND log2(e) so softmax uses exp2
          ((bf16*)Cout)[(size_t)row * N + col] =
              (bf16)((v * (1.0f + sc) + sh) * 0.18033688011112042f);
        } else {
          ((float*)Cout)[(size_t)row * N + col] = v;
        }
      }
    }
}

// ---------------------------------------------------------------------------
// Flash attention, split-K over keys. block = (b, h, qtile, split).
// Computes S^T = K·Q^T so each lane owns ONE query (col) and 4 consecutive
// keys per C-reg: per-lane scalar m/l, 2-shuffle reductions, packed b64 P
// writes. Online softmax in log2 domain. Unnormalized fp32 partials + (m,l).
// ---------------------------------------------------------------------------
__global__ __launch_bounds__(256) void attn_kernel(const bf16* __restrict__ q,
                                                   const bf16* __restrict__ kb,
                                                   const bf16* __restrict__ vt,
                                                   float* __restrict__ opA,
                                                   float* __restrict__ opB,
                                                   float* __restrict__ ml) {
  int b = blockIdx.z, h = blockIdx.y;
  int qt = blockIdx.x & 3, sp = blockIdx.x >> 2;
  int tid = threadIdx.x, lane = tid & 63, wv = tid >> 6;
  int quad = lane >> 4, lr = lane & 15;
  __shared__ __align__(16) bf16 Ks[64 * 64];
  __shared__ __align__(16) bf16 Vs[64 * 64];  // [dh][key]
  __shared__ __align__(16) bf16 QP[64 * 64];  // Q tile, then per-wave P scratch
  __shared__ float abuf[4][16];
  int q0 = qt * 64;

  const bf16* qg = q + (size_t)(b * N2 + q0) * INNER + h * DH;
  for (int j = 0; j < 2; j++) {
    int r0 = j * 32 + wv * 8;
    int r = r0 + (lane >> 3);
    async16(&qg[(size_t)r * INNER + ((lane & 7) ^ (r & 7)) * 8], &QP[r0 * 64]);
  }
  __syncthreads();
  bf16x8 aQ[2];
  {
    int row = wv * 16 + lr;
    for (int kk = 0; kk < 2; kk++)
      aQ[kk] = *(const bf16x8*)&QP[row * 64 + ((quad + 4 * kk) ^ (row & 7)) * 8];
  }
  float m_s = -1e30f, l_s = 0.0f;
  f32x4 oacc[4] = {};

  const bf16* kg = kb + (size_t)(b * N1) * 1024 + h * DH;
  const bf16* vg = vt + (size_t)((b * HEADS + h) * DH) * N1;
  bf16* Ps = QP + wv * 1024;  // wave-private 16 x 64

  for (int t = 0; t < KEYS_PER_SPLIT / 64; t++) {
    int key0 = sp * KEYS_PER_SPLIT + t * 64;
    __syncthreads();
    for (int j = 0; j < 2; j++) {
      int r0 = j * 32 + wv * 8;
      int r = r0 + (lane >> 3);
      int cs = ((lane & 7) ^ (r & 7)) * 8;
      async16(&kg[(size_t)(key0 + r) * 1024 + cs], &Ks[r0 * 64]);
      async16(&vg[(size_t)r * N1 + key0 + cs], &Vs[r0 * 64]);
    }
    __syncthreads();

    // S^T tiles: rows = keys (quad*4+r within 16nt), cols = queries (lr)
    f32x4 s[4] = {};
    for (int kk = 0; kk < 2; kk++)
      for (int nt = 0; nt < 4; nt++) {
        int row = nt * 16 + lr;
        bf16x8 ak =
            *(const bf16x8*)&Ks[row * 64 + ((quad + 4 * kk) ^ (row & 7)) * 8];
        s[nt] = __builtin_amdgcn_mfma_f32_16x16x32_bf16(ak, aQ[kk], s[nt], 0, 0, 0);
      }

    // per-lane softmax for query = lr (16 keys in regs, reduce across quads)
    float mx = s[0][0];
    for (int nt = 0; nt < 4; nt++)
      for (int r = 0; r < 4; r++) mx = fmaxf(mx, s[nt][r]);
    mx = fmaxf(mx, __shfl_xor(mx, 16, 64));
    mx = fmaxf(mx, __shfl_xor(mx, 32, 64));
    float mn = fmaxf(m_s, mx);
    float al = exp2f(m_s - mn);
    float p[4][4], sum = 0.0f;
    for (int nt = 0; nt < 4; nt++)
      for (int r = 0; r < 4; r++) {
        p[nt][r] = exp2f(s[nt][r] - mn);
        sum += p[nt][r];
      }
    sum += __shfl_xor(sum, 16, 64);
    sum += __shfl_xor(sum, 32, 64);
    l_s = l_s * al + sum;
    m_s = mn;
    if (quad == 0) abuf[wv][lr] = al;

    // packed P writes: P[query=lr][key=16nt+4quad+r], r=0..3 contiguous
    for (int nt = 0; nt < 4; nt++) {
      bf16x4 pk;
      for (int r = 0; r < 4; r++) pk[r] = (bf16)p[nt][r];
      *(bf16x4*)&Ps[lr * 64 + ((2 * nt + (quad >> 1)) ^ (lr & 7)) * 8 +
                    (quad & 1) * 4] = pk;
    }

    // rescale O accumulator (rows = query = quad*4+r)
    f32x4 a4 = *(const f32x4*)&abuf[wv][quad * 4];
    for (int in = 0; in < 4; in++)
      for (int r = 0; r < 4; r++) oacc[in][r] *= a4[r];

    bf16x8 aP[2];
    for (int kk = 0; kk < 2; kk++)
      aP[kk] = *(const bf16x8*)&Ps[lr * 64 + ((4 * kk + quad) ^ (lr & 7)) * 8];

    for (int kk = 0; kk < 2; kk++)
      for (int in = 0; in < 4; in++) {
        int row = in * 16 + lr;
        bf16x8 bv =
            *(const bf16x8*)&Vs[row * 64 + ((quad + 4 * kk) ^ (row & 7)) * 8];
        oacc[in] = __builtin_amdgcn_mfma_f32_16x16x32_bf16(aP[kk], bv, oacc[in], 0, 0, 0);
      }
  }

  float* ob = (sp < 2 ? opA : opB) + (size_t)(sp & 1) * SPLIT_ELEMS;
  size_t rbase = (size_t)(b * HEADS + h) * N2;
  for (int r = 0; r < 4; r++) {
    int qq = q0 + wv * 16 + quad * 4 + r;
    for (int in = 0; in < 4; in++)
      ob[(rbase + qq) * 64 + in * 16 + lr] = oacc[in][r];
  }
  if (quad == 0) {
    int qq = q0 + wv * 16 + lr;
    float* mlp = ml + ((size_t)sp * (4 * HEADS * N2) + rbase + qq) * 2;
    mlp[0] = m_s;
    mlp[1] = l_s;
  }
}

// ---------------------------------------------------------------------------
// Combine split-K partials: out = sum_s w_s O_s / sum_s w_s l_s, w_s=2^(m_s-M)
// ---------------------------------------------------------------------------
__global__ __launch_bounds__(256) void combine_kernel(const float* __restrict__ opA,
                                                      const float* __restrict__ opB,
                                                      const float* __restrict__ ml,
                                                      bf16* __restrict__ out) {
  int gid = blockIdx.x * 256 + threadIdx.x;
  int d = gid & 63;
  int rq = gid >> 6;  // (b*16+h)*256 + q
  int qq = rq & 255, bh = rq >> 8;
  int h = bh & 15, b = bh >> 4;
  float m[ASPLIT], l[ASPLIT];
  for (int s = 0; s < ASPLIT; s++) {
    const float* p = ml + ((size_t)s * (4 * HEADS * N2) + rq) * 2;
    m[s] = p[0];
    l[s] = p[1];
  }
  float M = fmaxf(fmaxf(m[0], m[1]), fmaxf(m[2], m[3]));
  float L = 0.0f, o = 0.0f;
  for (int s = 0; s < ASPLIT; s++) {
    float w = exp2f(m[s] - M);
    L += w * l[s];
    const float* op = (s < 2 ? opA : opB) + (size_t)(s & 1) * SPLIT_ELEMS;
    o += w * op[(size_t)rq * 64 + d];
  }
  out[((size_t)(b * N2 + qq)) * INNER + h * DH + d] = (bf16)(o / L);
}

// ---------------------------------------------------------------------------
extern "C" void kernel_launch(void* const* d_in, const int* in_sizes, int n_in,
                              void* d_out, int out_size, void* d_ws,
                              size_t ws_size, hipStream_t stream) {
  const float* x       = (const float*)d_in[0];
  const float* latents = (const float*)d_in[1];
  const float* shift   = (const float*)d_in[2];
  const float* scale   = (const float*)d_in[3];
  const float* ln1w    = (const float*)d_in[4];
  const float* ln1b    = (const float*)d_in[5];
  const float* ln2w    = (const float*)d_in[6];
  const float* ln2b    = (const float*)d_in[7];
  const float* Wq      = (const float*)d_in[8];
  const float* Wkv     = (const float*)d_in[9];
  const float* Wout    = (const float*)d_in[10];

  char* ws = (char*)d_ws;
  bf16*  xn    = (bf16*)(ws);                // 33.5MB; dead after kv gemm
  float* opA   = (float*)(ws);               //   overlay: splits 0,1 partials
  bf16*  lnl   = (bf16*)(ws + 33554432);     // 2MB; dead after q gemm
  float* ml    = (float*)(ws + 33554432);    //   overlay: (m,l) 0.5MB
  bf16*  qb    = (bf16*)(ws + 35651584);     // 2MB
  bf16*  kb    = (bf16*)(ws + 37748736);     // 33.5MB (K half)
  float* opB   = (float*)(ws + 71303168);    // 33.5MB: splits 2,3 partials
  bf16*  vtb   = (bf16*)(ws + 104857600);    // 33.5MB (V^T, written by kv gemm)
  bf16*  aob   = (bf16*)(ws + 138412032);    // 2MB
  bf16*  WqT   = (bf16*)(ws + 140509184);    // 2MB
  bf16*  WkvT  = (bf16*)(ws + 142606336);    // 4MB
  bf16*  WoutT = (bf16*)(ws + 146800640);    // 2MB -> total 148.9MB

  transpose_w_all<<<4096, dim3(32, 8), 0, stream>>>(Wq, Wkv, Wout, WqT, WkvT,
                                                    WoutT);
  ln_kernel<<<4096, 256, 0, stream>>>(x, ln1w, ln1b, xn);
  ln_kernel<<<256, 256, 0, stream>>>(latents, ln2w, ln2b, lnl);

  gemm_bf16<0><<<dim3(16, 128), 256, 0, stream>>>(xn, WkvT, kb, vtb, 16384,
                                                  2048, 1024, nullptr, nullptr);
  gemm_bf16<1><<<dim3(8, 8), 256, 0, stream>>>(lnl, WqT, qb, nullptr, 1024,
                                               1024, 1024, shift, scale);
  attn_kernel<<<dim3(4 * ASPLIT, 16, 4), 256, 0, stream>>>(qb, kb, vtb, opA,
                                                           opB, ml);
  combine_kernel<<<16384, 256, 0, stream>>>(opA, opB, ml, aob);
  gemm_bf16<2><<<dim3(8, 8), 256, 0, stream>>>(aob, WoutT, d_out, nullptr,
                                               1024, 1024, 1024, nullptr, nullptr);
}